// Round 2
// baseline (1050.837 us; speedup 1.0000x reference)
//
#include <hip/hip_runtime.h>

#define Bsz 512
#define Tsz 64
#define Hsz 512

typedef __attribute__((ext_vector_type(8))) short bf16x8;
typedef __attribute__((ext_vector_type(4))) float f32x4;

__device__ __forceinline__ unsigned short f2bf(float f) {
  union { float f; unsigned int u; } a; a.f = f;
  unsigned int u = a.u;
  unsigned int lsb = (u >> 16) & 1;
  u += 0x7fffu + lsb;   // round-to-nearest-even
  return (unsigned short)(u >> 16);
}

__device__ __forceinline__ void gload16(const void* g, void* l) {
  __builtin_amdgcn_global_load_lds(
      (const __attribute__((address_space(1))) unsigned int*)g,
      (__attribute__((address_space(3))) unsigned int*)l, 16, 0, 0);
}

__device__ __forceinline__ float sigm(float x) { return 1.f / (1.f + __expf(-x)); }
__device__ __forceinline__ float tanh_f(float x) { return 2.f / (1.f + __expf(-2.f * x)) - 1.f; }

// ---------------- converts ----------------
// x [B][T][I] f32 -> xbf [T][B][I] bf16
__global__ __launch_bounds__(256) void k_conv_x(const float* __restrict__ x,
                                                unsigned short* __restrict__ xbf) {
  int v = blockIdx.x * 256 + threadIdx.x;        // 0 .. 2097151
  int e = v * 8;
  int i = e & 511;
  int t = (e >> 9) & 63;
  int b = e >> 15;
  float4 f0 = *(const float4*)(x + e);
  float4 f1 = *(const float4*)(x + e + 4);
  bf16x8 o;
  o[0] = (short)f2bf(f0.x); o[1] = (short)f2bf(f0.y);
  o[2] = (short)f2bf(f0.z); o[3] = (short)f2bf(f0.w);
  o[4] = (short)f2bf(f1.x); o[5] = (short)f2bf(f1.y);
  o[6] = (short)f2bf(f1.z); o[7] = (short)f2bf(f1.w);
  *(bf16x8*)(xbf + ((size_t)(t * 512 + b) << 9) + i) = o;
}

// Wcat[d][slice][c][k] : c = g*32+hl -> w row g*512+slice*32+hl ; k<512 from w_ih, else w_hh
__global__ __launch_bounds__(256) void k_conv_w(
    const float* __restrict__ wihf, const float* __restrict__ whhf,
    const float* __restrict__ wihb, const float* __restrict__ whhb,
    const float* __restrict__ wlin,
    unsigned short* __restrict__ Wcat, unsigned short* __restrict__ wlinbf) {
  int v = blockIdx.x * 256 + threadIdx.x;
  const int nW = 2 * 16 * 128 * 128;             // 524288 vec8
  if (v < nW) {
    int k8 = v & 127; int row = v >> 7;          // row 0..4095
    int c = row & 127, sl = (row >> 7) & 15, d = row >> 11;
    int g = c >> 5, hl = c & 31;
    int wr = g * 512 + sl * 32 + hl;
    int k = k8 * 8;
    const float* src;
    if (k < 512) src = (d ? wihb : wihf) + (size_t)wr * 512 + k;
    else         src = (d ? whhb : whhf) + (size_t)wr * 512 + (k - 512);
    float4 f0 = *(const float4*)src;
    float4 f1 = *(const float4*)(src + 4);
    bf16x8 o;
    o[0] = (short)f2bf(f0.x); o[1] = (short)f2bf(f0.y);
    o[2] = (short)f2bf(f0.z); o[3] = (short)f2bf(f0.w);
    o[4] = (short)f2bf(f1.x); o[5] = (short)f2bf(f1.y);
    o[6] = (short)f2bf(f1.z); o[7] = (short)f2bf(f1.w);
    *(bf16x8*)(Wcat + (size_t)row * 1024 + k) = o;
  } else {
    int v2 = v - nW;                              // 0 .. 65535 : wlin [512][1024]
    const float* src = wlin + (size_t)v2 * 8;
    float4 f0 = *(const float4*)src;
    float4 f1 = *(const float4*)(src + 4);
    bf16x8 o;
    o[0] = (short)f2bf(f0.x); o[1] = (short)f2bf(f0.y);
    o[2] = (short)f2bf(f0.z); o[3] = (short)f2bf(f0.w);
    o[4] = (short)f2bf(f1.x); o[5] = (short)f2bf(f1.y);
    o[6] = (short)f2bf(f1.z); o[7] = (short)f2bf(f1.w);
    *(bf16x8*)(wlinbf + (size_t)v2 * 8) = o;
  }
}

// ---------------- LSTM step ----------------
// grid 256: blockIdx = mt*32 + (sl*2 + dir) ; tile [64 batch][128 cols = 4 gates x 32 hcols], K=1024
__global__ __launch_bounds__(256) void k_step(
    const unsigned short* __restrict__ xf, const unsigned short* __restrict__ xb,
    const unsigned short* __restrict__ hpf, const unsigned short* __restrict__ hpb,
    const unsigned short* __restrict__ Wcat,
    const float* __restrict__ biasf, const float* __restrict__ biasb,
    float* __restrict__ c_all,
    unsigned short* __restrict__ hof, unsigned short* __restrict__ hob) {
  extern __shared__ char smem[];                 // sA [64][64] @0 (8K), sB [128][64] @8192 (16K), sD [64][128] f32 @0 (32K)
  const int tid = threadIdx.x;
  const int g32 = blockIdx.x & 31;
  const int mt  = blockIdx.x >> 5;               // 0..7
  const int dir = g32 & 1;
  const int sl  = g32 >> 1;                      // 0..15
  const int b0  = mt * 64;

  const unsigned short* xd = dir ? xb : xf;
  const unsigned short* hd = dir ? hpb : hpf;
  const unsigned short* Wd = Wcat + (size_t)(dir * 16 + sl) * (128 * 1024);
  const float* bias = dir ? biasb : biasf;
  float* cd = c_all + (size_t)dir * (Bsz * Hsz);
  unsigned short* hod = dir ? hob : hof;

  const int lane = tid & 63;
  const int wv = tid >> 6;
  const int wr = wv >> 1, wc = wv & 1;
  const int l15 = lane & 15, l4 = lane >> 4;

  const f32x4 z4 = {0.f, 0.f, 0.f, 0.f};
  f32x4 acc[2][4];
#pragma unroll
  for (int i = 0; i < 2; ++i)
#pragma unroll
    for (int j = 0; j < 4; ++j) acc[i][j] = z4;

  for (int kc = 0; kc < 16; ++kc) {
    if (kc) __syncthreads();
    const unsigned short* Asrc = (kc < 8) ? xd : hd;
    const int kk = (kc & 7) * 64;
    // stage A [64][64] : 512 chunks of 16B, source cols pre-swizzled (inverse XOR)
#pragma unroll
    for (int it = 0; it < 2; ++it) {
      int idx = it * 256 + tid;
      int row = idx >> 3, c16 = idx & 7;
      int sc = c16 ^ (row & 7);
      gload16(Asrc + (size_t)(b0 + row) * 512 + kk + sc * 8, smem + idx * 16);
    }
    // stage B [128][64] : 1024 chunks
#pragma unroll
    for (int it = 0; it < 4; ++it) {
      int idx = it * 256 + tid;
      int row = idx >> 3, c16 = idx & 7;
      int sc = c16 ^ (row & 7);
      gload16(Wd + (size_t)row * 1024 + kc * 64 + sc * 8, smem + 8192 + idx * 16);
    }
    __syncthreads();
#pragma unroll
    for (int ks = 0; ks < 2; ++ks) {
      bf16x8 a[2], b[4];
      int sb = ks * 4 + l4;
#pragma unroll
      for (int mi = 0; mi < 2; ++mi) {
        int row = wr * 32 + mi * 16 + l15;
        a[mi] = *(const bf16x8*)(smem + row * 128 + (sb ^ (row & 7)) * 16);
      }
#pragma unroll
      for (int ni = 0; ni < 4; ++ni) {
        int row = wc * 64 + ni * 16 + l15;
        b[ni] = *(const bf16x8*)(smem + 8192 + row * 128 + (sb ^ (row & 7)) * 16);
      }
#pragma unroll
      for (int mi = 0; mi < 2; ++mi)
#pragma unroll
        for (int ni = 0; ni < 4; ++ni)
          acc[mi][ni] = __builtin_amdgcn_mfma_f32_16x16x32_bf16(a[mi], b[ni], acc[mi][ni], 0, 0, 0);
    }
  }
  __syncthreads();
  // dump acc -> sD [64][128] f32, bank-swizzled: col ^= ((row>>2)&3)<<4
  float* sD = (float*)smem;
#pragma unroll
  for (int mi = 0; mi < 2; ++mi)
#pragma unroll
    for (int ni = 0; ni < 4; ++ni) {
      int rowb = wr * 32 + mi * 16 + l4 * 4;
      int col = wc * 64 + ni * 16 + l15;
#pragma unroll
      for (int r = 0; r < 4; ++r) {
        int rr = rowb + r;
        sD[rr * 128 + (col ^ (((rr >> 2) & 3) << 4))] = acc[mi][ni][r];
      }
    }
  __syncthreads();
  // pointwise gate update: thread -> hl = tid&31, rows r0+8*ii
  const int hl = tid & 31;
  const int r0 = tid >> 5;
  const int hcg = sl * 32 + hl;
  const float bi = bias[hcg], bff = bias[512 + hcg], bg = bias[1024 + hcg], bo = bias[1536 + hcg];
#pragma unroll
  for (int ii = 0; ii < 8; ++ii) {
    int row = r0 + ii * 8;
    int sw = ((row >> 2) & 3) << 4;
    float iv = sD[row * 128 + ((0  + hl) ^ sw)] + bi;
    float fv = sD[row * 128 + ((32 + hl) ^ sw)] + bff;
    float gv = sD[row * 128 + ((64 + hl) ^ sw)] + bg;
    float ov = sD[row * 128 + ((96 + hl) ^ sw)] + bo;
    float ig = sigm(iv);
    float fg = sigm(fv);
    float gg = tanh_f(gv);
    float og = sigm(ov);
    size_t gi = (size_t)(b0 + row) * Hsz + hcg;
    float cn = fg * cd[gi] + ig * gg;
    cd[gi] = cn;
    float hn = og * tanh_f(cn);
    hod[gi] = f2bf(hn);
  }
}

// ---------------- output GEMM ----------------
// out[b,t,:] = [hs_f | hs_b](row r=t*512+b) @ wlin^T + blin ; grid 1024 = 256 mtiles x 4 ntiles
__global__ __launch_bounds__(256) void k_out(
    const unsigned short* __restrict__ hsf, const unsigned short* __restrict__ hsb,
    const unsigned short* __restrict__ wlin, const float* __restrict__ blin,
    float* __restrict__ out) {
  extern __shared__ char smem[];                 // sA [128][64] @0, sB [128][64] @16384
  const int tid = threadIdx.x;
  const int mt = blockIdx.x >> 2;
  const int nt = blockIdx.x & 3;
  const int m0 = mt * 128, n0 = nt * 128;
  const int lane = tid & 63, wv = tid >> 6;
  const int wr = wv >> 1, wc = wv & 1;
  const int l15 = lane & 15, l4 = lane >> 4;

  const f32x4 z4 = {0.f, 0.f, 0.f, 0.f};
  f32x4 acc[4][4];
#pragma unroll
  for (int i = 0; i < 4; ++i)
#pragma unroll
    for (int j = 0; j < 4; ++j) acc[i][j] = z4;

  for (int kc = 0; kc < 16; ++kc) {
    if (kc) __syncthreads();
    const unsigned short* Asrc = (kc < 8) ? hsf : hsb;
    const int kk = (kc & 7) * 64;
#pragma unroll
    for (int it = 0; it < 4; ++it) {
      int idx = it * 256 + tid;
      int row = idx >> 3, c16 = idx & 7;
      int sc = c16 ^ (row & 7);
      gload16(Asrc + (size_t)(m0 + row) * 512 + kk + sc * 8, smem + idx * 16);
    }
#pragma unroll
    for (int it = 0; it < 4; ++it) {
      int idx = it * 256 + tid;
      int row = idx >> 3, c16 = idx & 7;
      int sc = c16 ^ (row & 7);
      gload16(wlin + (size_t)(n0 + row) * 1024 + kc * 64 + sc * 8, smem + 16384 + idx * 16);
    }
    __syncthreads();
#pragma unroll
    for (int ks = 0; ks < 2; ++ks) {
      bf16x8 a[4], b[4];
      int sb = ks * 4 + l4;
#pragma unroll
      for (int mi = 0; mi < 4; ++mi) {
        int row = wr * 64 + mi * 16 + l15;
        a[mi] = *(const bf16x8*)(smem + row * 128 + (sb ^ (row & 7)) * 16);
      }
#pragma unroll
      for (int ni = 0; ni < 4; ++ni) {
        int row = wc * 64 + ni * 16 + l15;
        b[ni] = *(const bf16x8*)(smem + 16384 + row * 128 + (sb ^ (row & 7)) * 16);
      }
#pragma unroll
      for (int mi = 0; mi < 4; ++mi)
#pragma unroll
        for (int ni = 0; ni < 4; ++ni)
          acc[mi][ni] = __builtin_amdgcn_mfma_f32_16x16x32_bf16(a[mi], b[ni], acc[mi][ni], 0, 0, 0);
    }
  }
#pragma unroll
  for (int mi = 0; mi < 4; ++mi)
#pragma unroll
    for (int ni = 0; ni < 4; ++ni) {
      int cc = n0 + wc * 64 + ni * 16 + l15;
      float bl = blin[cc];
#pragma unroll
      for (int r = 0; r < 4; ++r) {
        int rr = m0 + wr * 64 + mi * 16 + l4 * 4 + r;
        int b = rr & 511, t = rr >> 9;
        out[(size_t)(b * 64 + t) * 512 + cc] = acc[mi][ni][r] + bl;
      }
    }
}

extern "C" void kernel_launch(void* const* d_in, const int* in_sizes, int n_in,
                              void* d_out, int out_size, void* d_ws, size_t ws_size,
                              hipStream_t stream) {
  const float* x     = (const float*)d_in[0];
  const float* wih_f = (const float*)d_in[1];
  const float* whh_f = (const float*)d_in[2];
  const float* b_f   = (const float*)d_in[3];
  const float* wih_b = (const float*)d_in[4];
  const float* whh_b = (const float*)d_in[5];
  const float* b_b   = (const float*)d_in[6];
  const float* wlin  = (const float*)d_in[7];
  const float* blin  = (const float*)d_in[8];
  float* out = (float*)d_out;

  char* ws = (char*)d_ws;
  unsigned short* Wcat   = (unsigned short*)(ws + 0);           // 8,388,608 B
  unsigned short* wlinbf = (unsigned short*)(ws + 8388608);     // 1,048,576 B
  unsigned short* xbf    = (unsigned short*)(ws + 9437184);     // 33,554,432 B
  unsigned short* hsf    = (unsigned short*)(ws + 42991616);    // 33,554,432 B
  unsigned short* hsb    = (unsigned short*)(ws + 76546048);    // 33,554,432 B
  float*          c_all  = (float*)(ws + 110100480);            // 2,097,152 B
  unsigned short* h0     = (unsigned short*)(ws + 112197632);   // 524,288 B

  hipMemsetAsync(c_all, 0, 2097152, stream);
  hipMemsetAsync(h0, 0, 524288, stream);
  k_conv_x<<<8192, 256, 0, stream>>>(x, xbf);
  k_conv_w<<<2304, 256, 0, stream>>>(wih_f, whh_f, wih_b, whh_b, wlin, Wcat, wlinbf);

  const size_t BH = (size_t)Bsz * Hsz;
  for (int s = 0; s < 64; ++s) {
    int tf = s, tb = 63 - s;
    const unsigned short* xfp = xbf + (size_t)tf * BH;
    const unsigned short* xbp = xbf + (size_t)tb * BH;
    const unsigned short* hpf = s ? hsf + (size_t)(tf - 1) * BH : h0;
    const unsigned short* hpb = s ? hsb + (size_t)(tb + 1) * BH : h0;
    k_step<<<256, 256, 32768, stream>>>(xfp, xbp, hpf, hpb, Wcat, b_f, b_b,
                                        c_all, hsf + (size_t)tf * BH, hsb + (size_t)tb * BH);
  }
  k_out<<<1024, 256, 32768, stream>>>(hsf, hsb, wlinbf, blin, out);
}

// Round 3
// 717.587 us; speedup vs baseline: 1.4644x; 1.4644x over previous
//
#include <hip/hip_runtime.h>

#define Bsz 512
#define Tsz 64
#define Hsz 512

typedef __attribute__((ext_vector_type(8))) short bf16x8;
typedef __attribute__((ext_vector_type(4))) float f32x4;

__device__ __forceinline__ unsigned short f2bf(float f) {
  union { float f; unsigned int u; } a; a.f = f;
  unsigned int u = a.u;
  unsigned int lsb = (u >> 16) & 1;
  u += 0x7fffu + lsb;   // round-to-nearest-even
  return (unsigned short)(u >> 16);
}

__device__ __forceinline__ void gload16(const void* g, void* l) {
  __builtin_amdgcn_global_load_lds(
      (const __attribute__((address_space(1))) unsigned int*)g,
      (__attribute__((address_space(3))) unsigned int*)l, 16, 0, 0);
}

__device__ __forceinline__ float sigm(float x) { return 1.f / (1.f + __expf(-x)); }
__device__ __forceinline__ float tanh_f(float x) { return 2.f / (1.f + __expf(-2.f * x)) - 1.f; }

// ---------------- converts ----------------
// x [B][T][I] f32 -> xbf [T][B][I] bf16
__global__ __launch_bounds__(256) void k_conv_x(const float* __restrict__ x,
                                                unsigned short* __restrict__ xbf) {
  int v = blockIdx.x * 256 + threadIdx.x;        // 0 .. 2097151
  int e = v * 8;
  int i = e & 511;
  int t = (e >> 9) & 63;
  int b = e >> 15;
  float4 f0 = *(const float4*)(x + e);
  float4 f1 = *(const float4*)(x + e + 4);
  bf16x8 o;
  o[0] = (short)f2bf(f0.x); o[1] = (short)f2bf(f0.y);
  o[2] = (short)f2bf(f0.z); o[3] = (short)f2bf(f0.w);
  o[4] = (short)f2bf(f1.x); o[5] = (short)f2bf(f1.y);
  o[6] = (short)f2bf(f1.z); o[7] = (short)f2bf(f1.w);
  *(bf16x8*)(xbf + ((size_t)(t * 512 + b) << 9) + i) = o;
}

// Wcat[d][slice][c][k] : c = g*32+hl -> w row g*512+slice*32+hl ; k<512 from w_ih, else w_hh
__global__ __launch_bounds__(256) void k_conv_w(
    const float* __restrict__ wihf, const float* __restrict__ whhf,
    const float* __restrict__ wihb, const float* __restrict__ whhb,
    const float* __restrict__ wlin,
    unsigned short* __restrict__ Wcat, unsigned short* __restrict__ wlinbf) {
  int v = blockIdx.x * 256 + threadIdx.x;
  const int nW = 2 * 16 * 128 * 128;             // 524288 vec8
  if (v < nW) {
    int k8 = v & 127; int row = v >> 7;          // row 0..4095
    int c = row & 127, sl = (row >> 7) & 15, d = row >> 11;
    int g = c >> 5, hl = c & 31;
    int wr = g * 512 + sl * 32 + hl;
    int k = k8 * 8;
    const float* src;
    if (k < 512) src = (d ? wihb : wihf) + (size_t)wr * 512 + k;
    else         src = (d ? whhb : whhf) + (size_t)wr * 512 + (k - 512);
    float4 f0 = *(const float4*)src;
    float4 f1 = *(const float4*)(src + 4);
    bf16x8 o;
    o[0] = (short)f2bf(f0.x); o[1] = (short)f2bf(f0.y);
    o[2] = (short)f2bf(f0.z); o[3] = (short)f2bf(f0.w);
    o[4] = (short)f2bf(f1.x); o[5] = (short)f2bf(f1.y);
    o[6] = (short)f2bf(f1.z); o[7] = (short)f2bf(f1.w);
    *(bf16x8*)(Wcat + (size_t)row * 1024 + k) = o;
  } else {
    int v2 = v - nW;                              // 0 .. 65535 : wlin [512][1024]
    const float* src = wlin + (size_t)v2 * 8;
    float4 f0 = *(const float4*)src;
    float4 f1 = *(const float4*)(src + 4);
    bf16x8 o;
    o[0] = (short)f2bf(f0.x); o[1] = (short)f2bf(f0.y);
    o[2] = (short)f2bf(f0.z); o[3] = (short)f2bf(f0.w);
    o[4] = (short)f2bf(f1.x); o[5] = (short)f2bf(f1.y);
    o[6] = (short)f2bf(f1.z); o[7] = (short)f2bf(f1.w);
    *(bf16x8*)(wlinbf + (size_t)v2 * 8) = o;
  }
}

// ---------------- LSTM step (pipelined: LDS double-buffer + counted vmcnt) ----------------
// grid 256: blockIdx = mt*32 + (sl*2 + dir) ; tile [64 batch][128 cols = 4 gates x 32 hcols], K=1024
// LDS: buf0 @0 (A[64][64] @0, B[128][64] @8192) = 24KB, buf1 @24576; epilogue sD f32[64][128] @0
__global__ __launch_bounds__(256) void k_step(
    const unsigned short* __restrict__ xf, const unsigned short* __restrict__ xb,
    const unsigned short* __restrict__ hpf, const unsigned short* __restrict__ hpb,
    const unsigned short* __restrict__ Wcat,
    const float* __restrict__ biasf, const float* __restrict__ biasb,
    float* __restrict__ c_all,
    unsigned short* __restrict__ hof, unsigned short* __restrict__ hob) {
  extern __shared__ char smem[];
  const int tid = threadIdx.x;
  const int g32 = blockIdx.x & 31;
  const int mt  = blockIdx.x >> 5;               // 0..7
  const int dir = g32 & 1;
  const int sl  = g32 >> 1;                      // 0..15
  const int b0  = mt * 64;

  const unsigned short* xd = dir ? xb : xf;
  const unsigned short* hd = dir ? hpb : hpf;
  const unsigned short* Wd = Wcat + (size_t)(dir * 16 + sl) * (128 * 1024);
  const float* bias = dir ? biasb : biasf;
  float* cd = c_all + (size_t)dir * (Bsz * Hsz);
  unsigned short* hod = dir ? hob : hof;

  const int lane = tid & 63;
  const int wv = tid >> 6;
  const int wr = wv >> 1, wc = wv & 1;
  const int l15 = lane & 15, l4 = lane >> 4;

  const f32x4 z4 = {0.f, 0.f, 0.f, 0.f};
  f32x4 acc[2][4];
#pragma unroll
  for (int i = 0; i < 2; ++i)
#pragma unroll
    for (int j = 0; j < 4; ++j) acc[i][j] = z4;

  // per-thread staging coordinates (fixed across kc)
  const int arow0 = tid >> 3;                    // A it=0 row (A it=1 row = +32)
  const int ac16  = tid & 7;

  // prologue: stage kc=0 into buf0
  {
    const unsigned short* Asrc = xd;
#pragma unroll
    for (int it = 0; it < 2; ++it) {
      int row = it * 32 + arow0;
      int sc = ac16 ^ (row & 7);
      gload16(Asrc + (size_t)(b0 + row) * 512 + 0 + sc * 8, smem + (it * 256 + tid) * 16);
    }
#pragma unroll
    for (int it = 0; it < 4; ++it) {
      int row = it * 32 + arow0;
      int sc = ac16 ^ (row & 7);
      gload16(Wd + (size_t)row * 1024 + 0 + sc * 8, smem + 8192 + (it * 256 + tid) * 16);
    }
  }

  for (int kc = 0; kc < 16; ++kc) {
    char* cur = smem + (kc & 1) * 24576;
    if (kc < 15) {
      // stage kc+1 into the other buffer (6 loads stay in flight across compute)
      char* nxt = smem + ((kc + 1) & 1) * 24576;
      int kn = kc + 1;
      const unsigned short* Asrc = (kn < 8) ? xd : hd;
      const int kk = (kn & 7) * 64;
#pragma unroll
      for (int it = 0; it < 2; ++it) {
        int row = it * 32 + arow0;
        int sc = ac16 ^ (row & 7);
        gload16(Asrc + (size_t)(b0 + row) * 512 + kk + sc * 8, nxt + (it * 256 + tid) * 16);
      }
#pragma unroll
      for (int it = 0; it < 4; ++it) {
        int row = it * 32 + arow0;
        int sc = ac16 ^ (row & 7);
        gload16(Wd + (size_t)row * 1024 + kn * 64 + sc * 8, nxt + 8192 + (it * 256 + tid) * 16);
      }
      asm volatile("s_waitcnt vmcnt(6)" ::: "memory");   // kc's 6 loads landed; kc+1's 6 in flight
    } else {
      asm volatile("s_waitcnt vmcnt(0)" ::: "memory");
    }
    __builtin_amdgcn_s_barrier();

#pragma unroll
    for (int ks = 0; ks < 2; ++ks) {
      bf16x8 a[2], b[4];
      int sb = ks * 4 + l4;
#pragma unroll
      for (int mi = 0; mi < 2; ++mi) {
        int row = wr * 32 + mi * 16 + l15;
        a[mi] = *(const bf16x8*)(cur + row * 128 + (sb ^ (row & 7)) * 16);
      }
#pragma unroll
      for (int ni = 0; ni < 4; ++ni) {
        int row = wc * 64 + ni * 16 + l15;
        b[ni] = *(const bf16x8*)(cur + 8192 + row * 128 + (sb ^ (row & 7)) * 16);
      }
#pragma unroll
      for (int mi = 0; mi < 2; ++mi)
#pragma unroll
        for (int ni = 0; ni < 4; ++ni)
          acc[mi][ni] = __builtin_amdgcn_mfma_f32_16x16x32_bf16(a[mi], b[ni], acc[mi][ni], 0, 0, 0);
    }
    asm volatile("s_waitcnt lgkmcnt(0)" ::: "memory");   // my reads of cur done
    __builtin_amdgcn_s_barrier();                        // buffer safe to restage
  }

  // dump acc -> sD [64][128] f32, bank-swizzled: col ^= ((row>>2)&3)<<4
  float* sD = (float*)smem;
#pragma unroll
  for (int mi = 0; mi < 2; ++mi)
#pragma unroll
    for (int ni = 0; ni < 4; ++ni) {
      int rowb = wr * 32 + mi * 16 + l4 * 4;
      int col = wc * 64 + ni * 16 + l15;
#pragma unroll
      for (int r = 0; r < 4; ++r) {
        int rr = rowb + r;
        sD[rr * 128 + (col ^ (((rr >> 2) & 3) << 4))] = acc[mi][ni][r];
      }
    }
  __syncthreads();
  // pointwise gate update: thread -> hl = tid&31, rows r0+8*ii
  const int hl = tid & 31;
  const int r0 = tid >> 5;
  const int hcg = sl * 32 + hl;
  const float bi = bias[hcg], bff = bias[512 + hcg], bg = bias[1024 + hcg], bo = bias[1536 + hcg];
#pragma unroll
  for (int ii = 0; ii < 8; ++ii) {
    int row = r0 + ii * 8;
    int sw = ((row >> 2) & 3) << 4;
    float iv = sD[row * 128 + ((0  + hl) ^ sw)] + bi;
    float fv = sD[row * 128 + ((32 + hl) ^ sw)] + bff;
    float gv = sD[row * 128 + ((64 + hl) ^ sw)] + bg;
    float ov = sD[row * 128 + ((96 + hl) ^ sw)] + bo;
    float ig = sigm(iv);
    float fg = sigm(fv);
    float gg = tanh_f(gv);
    float og = sigm(ov);
    size_t gi = (size_t)(b0 + row) * Hsz + hcg;
    float cn = fg * cd[gi] + ig * gg;
    cd[gi] = cn;
    float hn = og * tanh_f(cn);
    hod[gi] = f2bf(hn);
  }
}

// ---------------- output GEMM ----------------
// out[b,t,:] = [hs_f | hs_b](row r=t*512+b) @ wlin^T + blin ; grid 1024 = 256 mtiles x 4 ntiles
__global__ __launch_bounds__(256) void k_out(
    const unsigned short* __restrict__ hsf, const unsigned short* __restrict__ hsb,
    const unsigned short* __restrict__ wlin, const float* __restrict__ blin,
    float* __restrict__ out) {
  extern __shared__ char smem[];                 // sA [128][64] @0, sB [128][64] @16384
  const int tid = threadIdx.x;
  const int mt = blockIdx.x >> 2;
  const int nt = blockIdx.x & 3;
  const int m0 = mt * 128, n0 = nt * 128;
  const int lane = tid & 63, wv = tid >> 6;
  const int wr = wv >> 1, wc = wv & 1;
  const int l15 = lane & 15, l4 = lane >> 4;

  const f32x4 z4 = {0.f, 0.f, 0.f, 0.f};
  f32x4 acc[4][4];
#pragma unroll
  for (int i = 0; i < 4; ++i)
#pragma unroll
    for (int j = 0; j < 4; ++j) acc[i][j] = z4;

  for (int kc = 0; kc < 16; ++kc) {
    if (kc) __syncthreads();
    const unsigned short* Asrc = (kc < 8) ? hsf : hsb;
    const int kk = (kc & 7) * 64;
#pragma unroll
    for (int it = 0; it < 4; ++it) {
      int idx = it * 256 + tid;
      int row = idx >> 3, c16 = idx & 7;
      int sc = c16 ^ (row & 7);
      gload16(Asrc + (size_t)(m0 + row) * 512 + kk + sc * 8, smem + idx * 16);
    }
#pragma unroll
    for (int it = 0; it < 4; ++it) {
      int idx = it * 256 + tid;
      int row = idx >> 3, c16 = idx & 7;
      int sc = c16 ^ (row & 7);
      gload16(wlin + (size_t)(n0 + row) * 1024 + kc * 64 + sc * 8, smem + 16384 + idx * 16);
    }
    __syncthreads();
#pragma unroll
    for (int ks = 0; ks < 2; ++ks) {
      bf16x8 a[4], b[4];
      int sb = ks * 4 + l4;
#pragma unroll
      for (int mi = 0; mi < 4; ++mi) {
        int row = wr * 64 + mi * 16 + l15;
        a[mi] = *(const bf16x8*)(smem + row * 128 + (sb ^ (row & 7)) * 16);
      }
#pragma unroll
      for (int ni = 0; ni < 4; ++ni) {
        int row = wc * 64 + ni * 16 + l15;
        b[ni] = *(const bf16x8*)(smem + 16384 + row * 128 + (sb ^ (row & 7)) * 16);
      }
#pragma unroll
      for (int mi = 0; mi < 4; ++mi)
#pragma unroll
        for (int ni = 0; ni < 4; ++ni)
          acc[mi][ni] = __builtin_amdgcn_mfma_f32_16x16x32_bf16(a[mi], b[ni], acc[mi][ni], 0, 0, 0);
    }
  }
#pragma unroll
  for (int mi = 0; mi < 4; ++mi)
#pragma unroll
    for (int ni = 0; ni < 4; ++ni) {
      int cc = n0 + wc * 64 + ni * 16 + l15;
      float bl = blin[cc];
#pragma unroll
      for (int r = 0; r < 4; ++r) {
        int rr = m0 + wr * 64 + mi * 16 + l4 * 4 + r;
        int b = rr & 511, t = rr >> 9;
        out[(size_t)(b * 64 + t) * 512 + cc] = acc[mi][ni][r] + bl;
      }
    }
}

extern "C" void kernel_launch(void* const* d_in, const int* in_sizes, int n_in,
                              void* d_out, int out_size, void* d_ws, size_t ws_size,
                              hipStream_t stream) {
  const float* x     = (const float*)d_in[0];
  const float* wih_f = (const float*)d_in[1];
  const float* whh_f = (const float*)d_in[2];
  const float* b_f   = (const float*)d_in[3];
  const float* wih_b = (const float*)d_in[4];
  const float* whh_b = (const float*)d_in[5];
  const float* b_b   = (const float*)d_in[6];
  const float* wlin  = (const float*)d_in[7];
  const float* blin  = (const float*)d_in[8];
  float* out = (float*)d_out;

  char* ws = (char*)d_ws;
  unsigned short* Wcat   = (unsigned short*)(ws + 0);           // 8,388,608 B
  unsigned short* wlinbf = (unsigned short*)(ws + 8388608);     // 1,048,576 B
  unsigned short* xbf    = (unsigned short*)(ws + 9437184);     // 33,554,432 B
  unsigned short* hsf    = (unsigned short*)(ws + 42991616);    // 33,554,432 B
  unsigned short* hsb    = (unsigned short*)(ws + 76546048);    // 33,554,432 B
  float*          c_all  = (float*)(ws + 110100480);            // 2,097,152 B
  unsigned short* h0     = (unsigned short*)(ws + 112197632);   // 524,288 B

  hipMemsetAsync(c_all, 0, 2097152, stream);
  hipMemsetAsync(h0, 0, 524288, stream);
  k_conv_x<<<8192, 256, 0, stream>>>(x, xbf);
  k_conv_w<<<2304, 256, 0, stream>>>(wih_f, whh_f, wih_b, whh_b, wlin, Wcat, wlinbf);

  const size_t BH = (size_t)Bsz * Hsz;
  for (int s = 0; s < 64; ++s) {
    int tf = s, tb = 63 - s;
    const unsigned short* xfp = xbf + (size_t)tf * BH;
    const unsigned short* xbp = xbf + (size_t)tb * BH;
    const unsigned short* hpf = s ? hsf + (size_t)(tf - 1) * BH : h0;
    const unsigned short* hpb = s ? hsb + (size_t)(tb + 1) * BH : h0;
    k_step<<<256, 256, 49152, stream>>>(xfp, xbp, hpf, hpb, Wcat, b_f, b_b,
                                        c_all, hsf + (size_t)tf * BH, hsb + (size_t)tb * BH);
  }
  k_out<<<1024, 256, 32768, stream>>>(hsf, hsb, wlinbf, blin, out);
}